// Round 5
// baseline (10841.261 us; speedup 1.0000x reference)
//
#include <hip/hip_runtime.h>
#include <cstdint>
#include <cstddef>

#define NTAG 7

typedef unsigned int u32;
typedef unsigned long long u64;
using bf16x8 = __attribute__((ext_vector_type(8))) short;
using f32x4  = __attribute__((ext_vector_type(4))) float;

#define MFMA(A,B,C) __builtin_amdgcn_mfma_f32_16x16x32_bf16((A),(B),(C),0,0,0)

union abf { u64 q[2]; ushort e[8]; bf16x8 v; };

__device__ __forceinline__ u32 rtn_bf16(float f) {   // round-to-nearest-even
    u32 b = __float_as_uint(f);
    return (b + 0x7fffu + ((b >> 16) & 1u)) >> 16;
}

// ---------------------------------------------------------------------------
// Prep 1: fp32 -> bf16 (RTN) weight planes. order: 0=wif 1=whf 2=wib 3=whb
// ---------------------------------------------------------------------------
__global__ __launch_bounds__(256) void prep_w_kernel(
    const float* __restrict__ wif, const float* __restrict__ whf,
    const float* __restrict__ wib, const float* __restrict__ whb,
    ushort* __restrict__ planes)
{
    int f = blockIdx.x * 256 + threadIdx.x;          // x8 elems
    int mat = f >> 17;
    int i8 = (f & 0x1FFFF) << 3;
    const float* src = (mat == 0) ? wif : (mat == 1) ? whf : (mat == 2) ? wib : whb;
    float4 v0 = *(const float4*)(src + i8);
    float4 v1 = *(const float4*)(src + i8 + 4);
    ushort o[8];
    const float* pv = (const float*)&v0;
#pragma unroll
    for (int j = 0; j < 4; ++j) o[j] = (ushort)rtn_bf16(pv[j]);
    pv = (const float*)&v1;
#pragma unroll
    for (int j = 0; j < 4; ++j) o[4 + j] = (ushort)rtn_bf16(pv[j]);
    ushort* dst = planes + ((size_t)mat << 20) + i8;
    *(ushort4*)dst = make_ushort4(o[0], o[1], o[2], o[3]);
    *(ushort4*)(dst + 4) = make_ushort4(o[4], o[5], o[6], o[7]);
}

// ---------------------------------------------------------------------------
// Prep 2: xb[b][t][e] = bf16(emb[sent[b][t]][e])
// ---------------------------------------------------------------------------
__global__ __launch_bounds__(256) void prep_x_kernel(
    const int* __restrict__ sent, const float* __restrict__ emb,
    ushort* __restrict__ xb)
{
    long f = (long)blockIdx.x * 256 + threadIdx.x;   // x8 elems
    long e8 = f << 3;
    int bt = (int)(e8 >> 9);
    int e  = (int)(e8 & 511);
    int tok = sent[bt];
    const float* src = emb + (size_t)tok * 512 + e;
    float4 v0 = *(const float4*)(src);
    float4 v1 = *(const float4*)(src + 4);
    ushort o[8];
    const float* pv = (const float*)&v0;
#pragma unroll
    for (int j = 0; j < 4; ++j) o[j] = (ushort)rtn_bf16(pv[j]);
    pv = (const float*)&v1;
#pragma unroll
    for (int j = 0; j < 4; ++j) o[4 + j] = (ushort)rtn_bf16(pv[j]);
    ushort* dst = xb + e8;
    *(ushort4*)dst = make_ushort4(o[0], o[1], o[2], o[3]);
    *(ushort4*)(dst + 4) = make_ushort4(o[4], o[5], o[6], o[7]);
}

// ---------------------------------------------------------------------------
// Main persistent kernel, DUAL-DIRECTION per block: 64 blocks x 256 thr.
// block = (bq = blockIdx&3 -> 16 batches, slot = blockIdx>>2 -> 32 units).
// Each block runs BOTH direction chains, phase-alternated: while dir A
// computes its step, dir B's flag propagates and its 16KB h-tile streams
// in. Per phase tail: post flag -> (short) poll -> ISSUE 8 coherent u64
// stage loads -> x_phase (32 MFMA + 48 L2 loads covers the RTT) ->
// logits -> waitcnt -> swizzled LDS write. Stage loads are lane-contiguous
// 16B/thread (2 line-requests per 64B line, was 8 in R3). Logits: private
// per-(slot,dir) nt stores (Viterbi reduces); atomicAdd fallback.
// No inline asm (R4's int4-in-"v"-constraint compile error removed).
// ---------------------------------------------------------------------------
__global__ __launch_bounds__(256, 1) void lstm_mfma_kernel(
    const int* __restrict__ sent, const float* __restrict__ emb,
    const ushort* __restrict__ planes, const ushort* __restrict__ xb,
    const float* __restrict__ bif, const float* __restrict__ bhf,
    const float* __restrict__ bib, const float* __restrict__ bhb,
    const float* __restrict__ wout,
    const float* __restrict__ h0, const float* __restrict__ c0,
    ushort* __restrict__ hglob,   // [2 par][2 d][64 b][512] bf16
    float* __restrict__ logits,   // [512][64][7] atomic fallback
    float* __restrict__ partial,  // [512][64][32][7] private partials (opt)
    int* __restrict__ flags)      // [2 d][4 bq][16 slot] (64B line per (d,bq))
{
    __shared__ __align__(16) ushort hst0[16 * 512];   // 16KB dir0 stage (swz)
    __shared__ __align__(16) ushort hst1[16 * 512];   // 16KB dir1 stage (swz)
    __shared__ float sums_s[4 * 16 * 33];             // reused per phase
    __shared__ float hv_s[16 * 33];                   // reused per phase
    __shared__ float bias_s[2 * 128];
    __shared__ float wout_s[2 * 231];

    const int tid = threadIdx.x;
    const int w   = tid >> 6;       // wave = gate
    const int L   = tid & 63;
    const int ln  = L & 15;
    const int lk  = L >> 4;
    const int bq  = blockIdx.x & 3;
    const int slot= blockIdx.x >> 2;
    const int B0  = bq << 4;
    const int u0  = slot << 5;

    const ushort* wip0 = planes;
    const ushort* whp0 = planes + ((size_t)1 << 20);
    const ushort* wip1 = planes + ((size_t)2 << 20);
    const ushort* whp1 = planes + ((size_t)3 << 20);

    // register-resident W_hh B-frags for BOTH dirs (256 VGPRs)
    bf16x8 Bh[2][2][16];
#pragma unroll
    for (int dd = 0; dd < 2; ++dd) {
        const ushort* whp = dd ? whp1 : whp0;
#pragma unroll
        for (int h = 0; h < 2; ++h) {
            const size_t row = (size_t)(w * 512 + u0 + h * 16 + ln);
#pragma unroll
            for (int kb = 0; kb < 16; ++kb)
                Bh[dd][h][kb] = *(const bf16x8*)(whp + row * 512 + kb * 32 + lk * 8);
        }
    }
    {   // bias: [d][gate][u]  (256 entries, one per thread)
        int dd = tid >> 7, idx = tid & 127;
        int gg = idx >> 5, uu = idx & 31;
        int grow = gg * 512 + u0 + uu;
        bias_s[tid] = dd ? (bib[grow] + bhb[grow]) : (bif[grow] + bhf[grow]);
    }
    for (int idx = tid; idx < 448; idx += 256) {
        int dd = idx / 224, r = idx - dd * 224;
        int tg = r >> 5, uu = r & 31;
        wout_s[dd * 231 + tg * 33 + uu] = wout[(size_t)tg * 1024 + dd * 512 + u0 + uu];
    }
    // c-state, both dirs: thread -> (b = tid>>4, units uh*2, uh*2+1)
    const int cb = tid >> 4, uh = tid & 15;
    float cst[2][2];
#pragma unroll
    for (int dd = 0; dd < 2; ++dd) {
        const float* cr = c0 + ((size_t)(dd * 64) + B0 + cb) * 512 + u0 + uh * 2;
        cst[dd][0] = cr[0]; cst[dd][1] = cr[1];
    }
    __syncthreads();

    const int gb = B0 + ln;                 // this lane's global batch
    const int hx = (ln & 7) << 4;           // stage read-side row swizzle
    f32x4 xacc0_0, xacc1_0, xacc0_1, xacc1_1;

    // x-phase: accumulates x_t . W_ih^T for one dir (W streamed from L2)
    auto x_phase = [&](const ushort* wipD, int tnext, f32x4& xo0, f32x4& xo1) {
        f32x4 a0a = {0,0,0,0}, a0b = {0,0,0,0}, a1a = {0,0,0,0}, a1b = {0,0,0,0};
        const size_t row0 = (size_t)(w * 512 + u0 + ln);
        const size_t row1 = row0 + 16;
#pragma unroll
        for (int kb = 0; kb < 16; ++kb) {
            bf16x8 A;
            if (xb) {
                A = *(const bf16x8*)(xb + ((size_t)gb * 512 + tnext) * 512 + kb * 32 + lk * 8);
            } else {
                int tok = sent[gb * 512 + tnext];
                const float* xr = emb + (size_t)tok * 512 + kb * 32 + lk * 8;
                float4 f0 = *(const float4*)(xr);
                float4 f1 = *(const float4*)(xr + 4);
                abf t;
                const float* pv = (const float*)&f0;
#pragma unroll
                for (int j = 0; j < 4; ++j) t.e[j] = (ushort)rtn_bf16(pv[j]);
                pv = (const float*)&f1;
#pragma unroll
                for (int j = 0; j < 4; ++j) t.e[4 + j] = (ushort)rtn_bf16(pv[j]);
                A = t.v;
            }
            bf16x8 Bx0 = *(const bf16x8*)(wipD + row0 * 512 + kb * 32 + lk * 8);
            bf16x8 Bx1 = *(const bf16x8*)(wipD + row1 * 512 + kb * 32 + lk * 8);
            if (kb & 1) { a0b = MFMA(A, Bx0, a0b); a1b = MFMA(A, Bx1, a1b); }
            else        { a0a = MFMA(A, Bx0, a0a); a1a = MFMA(A, Bx1, a1a); }
        }
        xo0 = a0a + a0b;
        xo1 = a1a + a1b;
    };

    x_phase(wip1, 511, xacc0_1, xacc1_1);
    x_phase(wip0, 0,   xacc0_0, xacc1_0);

#define AL(P) __hip_atomic_load((P), __ATOMIC_RELAXED, __HIP_MEMORY_SCOPE_AGENT)

#define LOGITS(DD, TT)                                                         \
    if (tid >= 144) {                                                          \
        int q_ = tid - 144, tg_ = q_ >> 4, b_ = q_ & 15;                       \
        float a_ = 0.f;                                                        \
        _Pragma("unroll")                                                      \
        for (int u = 0; u < 32; ++u)                                           \
            a_ = fmaf(hv_s[b_ * 33 + u], wout_s[(DD) * 231 + tg_ * 33 + u], a_);\
        if (partial)                                                           \
            __builtin_nontemporal_store(a_, partial +                          \
                ((size_t)(TT) * 64 + B0 + b_) * 224 + (slot * 2 + (DD)) * 7 + tg_);\
        else                                                                   \
            atomicAdd(&logits[((size_t)(TT) * 64 + B0 + b_) * NTAG + tg_], a_);\
    }

#define PHASE(DD, OD, TCUR, THR, WIPDD, HSTDD, HSTOD)                          \
    {                                                                          \
        const int tcur_ = (TCUR);                                              \
        f32x4 f0a = xacc0_##DD, f0b = {0,0,0,0};                               \
        f32x4 f1a = xacc1_##DD, f1b = {0,0,0,0};                               \
        if (s == 0) {                                                          \
            const float* hr = h0 + ((size_t)((DD) * 64) + gb) * 512;           \
            _Pragma("unroll")                                                  \
            for (int kb = 0; kb < 16; ++kb) {                                  \
                float4 q0 = *(const float4*)(hr + kb * 32 + lk * 8);           \
                float4 q1 = *(const float4*)(hr + kb * 32 + lk * 8 + 4);       \
                abf A; const float* pv = (const float*)&q0;                    \
                _Pragma("unroll")                                              \
                for (int j = 0; j < 4; ++j) A.e[j] = (ushort)rtn_bf16(pv[j]);  \
                pv = (const float*)&q1;                                        \
                _Pragma("unroll")                                              \
                for (int j = 0; j < 4; ++j) A.e[4+j] = (ushort)rtn_bf16(pv[j]);\
                if (kb & 1) { f0b = MFMA(A.v, Bh[DD][0][kb], f0b);             \
                              f1b = MFMA(A.v, Bh[DD][1][kb], f1b); }           \
                else        { f0a = MFMA(A.v, Bh[DD][0][kb], f0a);             \
                              f1a = MFMA(A.v, Bh[DD][1][kb], f1a); }           \
            }                                                                  \
        } else {                                                               \
            const char* hsb = (const char*)(HSTDD);                            \
            _Pragma("unroll")                                                  \
            for (int kb = 0; kb < 16; ++kb) {                                  \
                abf A;                                                         \
                A.v = *(const bf16x8*)(hsb + ln * 1024 +                       \
                                       ((kb * 64 + lk * 16) ^ hx));            \
                if (kb & 1) { f0b = MFMA(A.v, Bh[DD][0][kb], f0b);             \
                              f1b = MFMA(A.v, Bh[DD][1][kb], f1b); }           \
                else        { f0a = MFMA(A.v, Bh[DD][0][kb], f0a);             \
                              f1a = MFMA(A.v, Bh[DD][1][kb], f1a); }           \
            }                                                                  \
        }                                                                      \
        f32x4 g0 = f0a + f0b, g1 = f1a + f1b;                                  \
        _Pragma("unroll")                                                      \
        for (int r = 0; r < 4; ++r) {                                          \
            int b = lk * 4 + r;                                                \
            sums_s[w * 528 + b * 33 + ln]      = g0[r];                        \
            sums_s[w * 528 + b * 33 + 16 + ln] = g1[r];                        \
        }                                                                      \
        __syncthreads();                                                       \
        {                                                                      \
            u32 pk = 0;                                                        \
            _Pragma("unroll")                                                  \
            for (int e = 0; e < 2; ++e) {                                      \
                int u = uh * 2 + e;                                            \
                float si = sums_s[0 * 528 + cb * 33 + u] + bias_s[(DD)*128 + u];      \
                float sf = sums_s[1 * 528 + cb * 33 + u] + bias_s[(DD)*128 + 32 + u]; \
                float sg = sums_s[2 * 528 + cb * 33 + u] + bias_s[(DD)*128 + 64 + u]; \
                float so = sums_s[3 * 528 + cb * 33 + u] + bias_s[(DD)*128 + 96 + u]; \
                float ig = 1.f / (1.f + expf(-si));                            \
                float fg = 1.f / (1.f + expf(-sf));                            \
                float gv = tanhf(sg);                                          \
                float og = 1.f / (1.f + expf(-so));                            \
                float cn = fg * cst[DD][e] + ig * gv;                          \
                cst[DD][e] = cn;                                               \
                float hh = og * tanhf(cn);                                     \
                hv_s[cb * 33 + u] = hh;                                        \
                pk |= rtn_bf16(hh) << (16 * e);                                \
            }                                                                  \
            u32* dst = (u32*)(hglob + ((size_t)(((s + 1) & 1) * 2 + (DD)) * 64 \
                              + B0 + cb) * 512 + u0 + uh * 2);                 \
            __hip_atomic_store(dst, pk, __ATOMIC_RELAXED,                      \
                               __HIP_MEMORY_SCOPE_AGENT);                      \
        }                                                                      \
        __syncthreads();                                                       \
        __builtin_amdgcn_s_waitcnt(0);                                         \
        __syncthreads();                                                       \
        if (s < 511 && tid == 0)                                               \
            __hip_atomic_store(flags + (((DD) * 4 + bq) << 4) + slot, s + 1,   \
                               __ATOMIC_RELAXED, __HIP_MEMORY_SCOPE_AGENT);    \
        const int thr_ = (THR);                                                \
        const bool dostage_ = (thr_ >= 1 && thr_ <= 511);                      \
        if (dostage_ && w == 0) {                                              \
            const int* fp = flags + (((OD) * 4 + bq) << 4) + ln;               \
            while (true) {                                                     \
                int v = __hip_atomic_load(fp, __ATOMIC_RELAXED,                \
                                          __HIP_MEMORY_SCOPE_AGENT);           \
                if (__all(v >= thr_)) break;                                   \
                __builtin_amdgcn_s_sleep(1);                                   \
            }                                                                  \
        }                                                                      \
        __syncthreads();                                                       \
        u64 sv0 = 0, sv1 = 0, sv2 = 0, sv3 = 0, sv4 = 0, sv5 = 0, sv6 = 0, sv7 = 0; \
        const u64* hq_ = (const u64*)(hglob +                                  \
            ((size_t)((thr_ & 1) * 2 + (OD)) * 64 + B0) * 512);                \
        if (dostage_) {   /* lane-contiguous 16B/thread x 4 passes */          \
            sv0 = AL(hq_ + tid * 2);         sv1 = AL(hq_ + tid * 2 + 1);      \
            sv2 = AL(hq_ + 512 + tid * 2);   sv3 = AL(hq_ + 512 + tid * 2 + 1);\
            sv4 = AL(hq_ + 1024 + tid * 2);  sv5 = AL(hq_ + 1024 + tid * 2 + 1);\
            sv6 = AL(hq_ + 1536 + tid * 2);  sv7 = AL(hq_ + 1536 + tid * 2 + 1);\
        }                                                                      \
        if (s < 511)                                                           \
            x_phase(WIPDD, (DD) ? (510 - s) : (s + 1),                         \
                    xacc0_##DD, xacc1_##DD);                                   \
        LOGITS(DD, tcur_)                                                      \
        if (dostage_) {                                                        \
            __builtin_amdgcn_s_waitcnt(0);                                     \
            __builtin_amdgcn_sched_barrier(0);                                 \
            char* hd_ = (char*)(HSTOD);                                        \
            const int c_ = (tid & 63) * 16;                                    \
            const int r_ = tid >> 6;                                           \
            {                                                                  \
                int rr = r_;                                                   \
                char* a = hd_ + rr * 1024 + (c_ ^ ((rr & 7) << 4));            \
                *(u64*)a = sv0; *(u64*)(a + 8) = sv1;                          \
            }                                                                  \
            {                                                                  \
                int rr = r_ + 4;                                               \
                char* a = hd_ + rr * 1024 + (c_ ^ ((rr & 7) << 4));            \
                *(u64*)a = sv2; *(u64*)(a + 8) = sv3;                          \
            }                                                                  \
            {                                                                  \
                int rr = r_ + 8;                                               \
                char* a = hd_ + rr * 1024 + (c_ ^ ((rr & 7) << 4));            \
                *(u64*)a = sv4; *(u64*)(a + 8) = sv5;                          \
            }                                                                  \
            {                                                                  \
                int rr = r_ + 12;                                              \
                char* a = hd_ + rr * 1024 + (c_ ^ ((rr & 7) << 4));            \
                *(u64*)a = sv6; *(u64*)(a + 8) = sv7;                          \
            }                                                                  \
        }                                                                      \
        __syncthreads();                                                       \
    }

    for (int s = 0; s < 512; ++s) {
        // PHASE A: compute dir1 step s; prefetch/stage dir0's h (step s)
        PHASE(1, 0, 511 - s, s, wip1, hst1, hst0)
        // PHASE B: compute dir0 step s; prefetch/stage dir1's h (step s+1)
        PHASE(0, 1, s, s + 1, wip0, hst0, hst1)
    }
#undef PHASE
#undef LOGITS
#undef AL
}

// ---------------------------------------------------------------------------
// Viterbi decode: one wave per batch (lanes 0..6 = tags), byte backpointers.
// If `partial` is set, first reduce the 32 per-(slot,dir) partials.
// ---------------------------------------------------------------------------
__global__ __launch_bounds__(256) void viterbi_kernel(
    const float* __restrict__ logits, const float* __restrict__ partial,
    const float* __restrict__ bout, const float* __restrict__ trans,
    unsigned char* __restrict__ bp,   // [64][512][8]
    float* __restrict__ out)          // [64 scores][64*512 paths]
{
    __shared__ float Ls[4][512][7];
    const int tid = threadIdx.x;
    const int b0 = blockIdx.x << 2;

    if (partial) {
        for (int idx2 = tid; idx2 < 2048; idx2 += 256) {
            int bl = idx2 >> 9, t = idx2 & 511;
            const float* pp = partial + ((size_t)t * 64 + b0 + bl) * 224;
            float a0=0,a1=0,a2=0,a3=0,a4=0,a5=0,a6=0;
#pragma unroll 8
            for (int c = 0; c < 32; ++c) {
                const float* q = pp + c * 7;
                a0 += q[0]; a1 += q[1]; a2 += q[2]; a3 += q[3];
                a4 += q[4]; a5 += q[5]; a6 += q[6];
            }
            Ls[bl][t][0] = a0 + bout[0]; Ls[bl][t][1] = a1 + bout[1];
            Ls[bl][t][2] = a2 + bout[2]; Ls[bl][t][3] = a3 + bout[3];
            Ls[bl][t][4] = a4 + bout[4]; Ls[bl][t][5] = a5 + bout[5];
            Ls[bl][t][6] = a6 + bout[6];
        }
    } else {
        for (int idx = tid; idx < 4 * 512 * 7; idx += 256) {
            int bl = idx / 3584;
            int rem = idx - bl * 3584;
            int t = rem / 7;
            int tg = rem - t * 7;
            Ls[bl][t][tg] = logits[((size_t)t * 64 + b0 + bl) * 7 + tg] + bout[tg];
        }
    }
    __syncthreads();

    const int w = tid >> 6;
    const int lane = tid & 63;
    const int b = b0 + w;
    const int k = lane;

    float tr[7];
#pragma unroll
    for (int j = 0; j < 7; ++j) tr[j] = (k < 7) ? trans[j * 7 + k] : -1e30f;
    float prev = (k < 7) ? Ls[w][0][k] : -1e30f;
    unsigned char* bpb = bp + (size_t)b * 512 * 8;

    for (int t = 1; t < 512; ++t) {
        float best = __shfl(prev, 0, 64) + tr[0];
        int bj = 0;
#pragma unroll
        for (int j = 1; j < 7; ++j) {
            float v = __shfl(prev, j, 64) + tr[j];
            if (v > best) { best = v; bj = j; }   // strict > = first argmax
        }
        float lv = (k < 7) ? Ls[w][t][k] : 0.f;
        if (k < 7) bpb[t * 8 + k] = (unsigned char)bj;
        prev = lv + best;
    }

    float pv[7];
#pragma unroll
    for (int j = 0; j < 7; ++j) pv[j] = __shfl(prev, j, 64);
    float best = pv[0]; int bj = 0;
#pragma unroll
    for (int j = 1; j < 7; ++j) if (pv[j] > best) { best = pv[j]; bj = j; }
    if (lane == 0) {
        out[b] = best;
        out[64 + (size_t)b * 512 + 511] = (float)bj;
    }

    int cur = bj;
    for (int tc = 448; tc >= 0; tc -= 64) {
        int t = tc + lane;
        u64 row = *(const u64*)(bpb + (size_t)t * 8);
        for (int i = 63; i >= 0; --i) {
            int t2 = tc + i;
            if (t2 < 1) break;
            u64 r = __shfl(row, i, 64);
            cur = (int)((r >> (cur * 8)) & 0xFF);
            if (lane == 0) out[64 + (size_t)b * 512 + (t2 - 1)] = (float)cur;
        }
    }
}

// ---------------------------------------------------------------------------
extern "C" void kernel_launch(void* const* d_in, const int* in_sizes, int n_in,
                              void* d_out, int out_size, void* d_ws, size_t ws_size,
                              hipStream_t stream)
{
    (void)in_sizes; (void)n_in; (void)out_size;
    const int*   sent = (const int*)d_in[0];
    const float* emb  = (const float*)d_in[1];
    const float* wif  = (const float*)d_in[2];
    const float* whf  = (const float*)d_in[3];
    const float* bif  = (const float*)d_in[4];
    const float* bhf  = (const float*)d_in[5];
    const float* wib  = (const float*)d_in[6];
    const float* whb  = (const float*)d_in[7];
    const float* bib  = (const float*)d_in[8];
    const float* bhb  = (const float*)d_in[9];
    const float* wout = (const float*)d_in[10];
    const float* bout = (const float*)d_in[11];
    const float* h0   = (const float*)d_in[12];
    const float* c0   = (const float*)d_in[13];
    const float* trans= (const float*)d_in[14];
    float* out = (float*)d_out;

    // ws: logits(917504) | flags(8192; 128 used) | hglob(262144) | bp(262144)
    //     | planes(8MB) | xb(32MB opt) | partial(29.36MB opt)
    char* p = (char*)d_ws;
    float*  logits = (float*)p;            p += 917504;
    int*    flags  = (int*)p;              p += 8192;
    ushort* hglob  = (ushort*)p;           p += 2 * 2 * 64 * 512 * 2;   // 262144
    unsigned char* bp = (unsigned char*)p; p += 262144;
    ushort* planes = (ushort*)p;           p += 4 * 1048576 * 2;        // 8 MB
    size_t base_need = (size_t)(p - (char*)d_ws);
    ushort* xb = nullptr;
    float*  partial = nullptr;
    if (ws_size >= base_need + (size_t)64 * 512 * 512 * 2) {
        xb = (ushort*)p;  p += (size_t)64 * 512 * 512 * 2;              // 32 MB
        if (ws_size >= (size_t)(p - (char*)d_ws) + (size_t)512 * 64 * 224 * 4)
            partial = (float*)p;                                        // 29.36 MB
    }

    hipMemsetAsync(d_ws, 0, 917504 + 8192, stream);   // logits + flags
    prep_w_kernel<<<2048, 256, 0, stream>>>(wif, whf, wib, whb, planes);
    if (xb) prep_x_kernel<<<8192, 256, 0, stream>>>(sent, emb, xb);
    lstm_mfma_kernel<<<64, 256, 0, stream>>>(
        sent, emb, planes, xb, bif, bhf, bib, bhb,
        wout, h0, c0, hglob, logits, partial, flags);
    viterbi_kernel<<<16, 256, 0, stream>>>(logits, partial, bout, trans, bp, out);
}

// Round 6
// 5315.676 us; speedup vs baseline: 2.0395x; 2.0395x over previous
//
#include <hip/hip_runtime.h>
#include <cstdint>
#include <cstddef>

#define NTAG 7

typedef unsigned int u32;
typedef unsigned long long u64;
using bf16x8 = __attribute__((ext_vector_type(8))) short;
using f32x4  = __attribute__((ext_vector_type(4))) float;

#define MFMA(A,B,C) __builtin_amdgcn_mfma_f32_16x16x32_bf16((A),(B),(C),0,0,0)

union abf { u64 q[2]; ushort e[8]; bf16x8 v; };

__device__ __forceinline__ u32 rtn_bf16(float f) {   // round-to-nearest-even
    u32 b = __float_as_uint(f);
    return (b + 0x7fffu + ((b >> 16) & 1u)) >> 16;
}

// ---------------------------------------------------------------------------
// Prep 1: fp32 -> bf16 (RTN) weight planes. order: 0=wif 1=whf 2=wib 3=whb
// ---------------------------------------------------------------------------
__global__ __launch_bounds__(256) void prep_w_kernel(
    const float* __restrict__ wif, const float* __restrict__ whf,
    const float* __restrict__ wib, const float* __restrict__ whb,
    ushort* __restrict__ planes)
{
    int f = blockIdx.x * 256 + threadIdx.x;          // x8 elems
    int mat = f >> 17;
    int i8 = (f & 0x1FFFF) << 3;
    const float* src = (mat == 0) ? wif : (mat == 1) ? whf : (mat == 2) ? wib : whb;
    float4 v0 = *(const float4*)(src + i8);
    float4 v1 = *(const float4*)(src + i8 + 4);
    ushort o[8];
    const float* pv = (const float*)&v0;
#pragma unroll
    for (int j = 0; j < 4; ++j) o[j] = (ushort)rtn_bf16(pv[j]);
    pv = (const float*)&v1;
#pragma unroll
    for (int j = 0; j < 4; ++j) o[4 + j] = (ushort)rtn_bf16(pv[j]);
    ushort* dst = planes + ((size_t)mat << 20) + i8;
    *(ushort4*)dst = make_ushort4(o[0], o[1], o[2], o[3]);
    *(ushort4*)(dst + 4) = make_ushort4(o[4], o[5], o[6], o[7]);
}

// ---------------------------------------------------------------------------
// Prep 2: xb[b][t][e] = bf16(emb[sent[b][t]][e])
// ---------------------------------------------------------------------------
__global__ __launch_bounds__(256) void prep_x_kernel(
    const int* __restrict__ sent, const float* __restrict__ emb,
    ushort* __restrict__ xb)
{
    long f = (long)blockIdx.x * 256 + threadIdx.x;   // x8 elems
    long e8 = f << 3;
    int bt = (int)(e8 >> 9);
    int e  = (int)(e8 & 511);
    int tok = sent[bt];
    const float* src = emb + (size_t)tok * 512 + e;
    float4 v0 = *(const float4*)(src);
    float4 v1 = *(const float4*)(src + 4);
    ushort o[8];
    const float* pv = (const float*)&v0;
#pragma unroll
    for (int j = 0; j < 4; ++j) o[j] = (ushort)rtn_bf16(pv[j]);
    pv = (const float*)&v1;
#pragma unroll
    for (int j = 0; j < 4; ++j) o[4 + j] = (ushort)rtn_bf16(pv[j]);
    ushort* dst = xb + e8;
    *(ushort4*)dst = make_ushort4(o[0], o[1], o[2], o[3]);
    *(ushort4*)(dst + 4) = make_ushort4(o[4], o[5], o[6], o[7]);
}

// ---------------------------------------------------------------------------
// Main persistent kernel: 128 blocks x 256 thr (4 waves), 1 block/CU.
// group g = blockIdx&7 = (dir d, batch-quarter bq: 16 batches); slot =
// blockIdx>>3 -> 32 units. wave w = gate w, 2 n-tiles of 16 units.
// R3 protocol (proven 5332us) with 3 reorders:
//  - h-store drain hidden under logits+x_phase (waitcnt AFTER x_phase)
//  - logits -> private per-(slot,dir) nt partial stores every step
//    (no RMW contention; acks covered by x_phase); Viterbi reduces
//  - stage loads lane-contiguous 16B/thread (perfect MALL coalescing)
// ---------------------------------------------------------------------------
__global__ __launch_bounds__(256, 1) void lstm_mfma_kernel(
    const int* __restrict__ sent, const float* __restrict__ emb,
    const ushort* __restrict__ planes, const ushort* __restrict__ xb,
    const float* __restrict__ bif, const float* __restrict__ bhf,
    const float* __restrict__ bib, const float* __restrict__ bhb,
    const float* __restrict__ wout,
    const float* __restrict__ h0, const float* __restrict__ c0,
    ushort* __restrict__ hglob,   // [2 par][2 d][64 b][512] bf16
    float* __restrict__ logits,   // [512][64][7] atomic fallback
    float* __restrict__ partial,  // [512][64][32][7] private partials (opt)
    int* __restrict__ flags)      // [8 g][16 slot]  (one 64B line per group)
{
    __shared__ __align__(16) ushort hstage[16 * 512];   // 16384 B, XOR-swz rows
    __shared__ float sums_s[4 * 16 * 33];               //  8448 B
    __shared__ float hv_s[16 * 33];                     //  2112 B
    __shared__ float bias_s[4 * 32];                    //   512 B
    __shared__ float wout_s[7 * 33];                    //   924 B

    const int tid = threadIdx.x;
    const int w   = tid >> 6;       // wave = gate
    const int L   = tid & 63;
    const int ln  = L & 15;
    const int lk  = L >> 4;
    const int g   = blockIdx.x & 7;
    const int slot= blockIdx.x >> 3;
    const int d   = g & 1;
    const int bq  = g >> 1;
    const int B0  = bq << 4;
    const int u0  = slot << 5;

    const ushort* wip = planes + ((size_t)(d ? 2 : 0) << 20);
    const ushort* whp = planes + ((size_t)(d ? 3 : 1) << 20);

    // register-resident W_hh B-frags: rows = gate w, units u0 + h*16 + ln
    bf16x8 Bh[2][16];
#pragma unroll
    for (int h = 0; h < 2; ++h) {
        const size_t row = (size_t)(w * 512 + u0 + h * 16 + ln);
#pragma unroll
        for (int kb = 0; kb < 16; ++kb)
            Bh[h][kb] = *(const bf16x8*)(whp + row * 512 + kb * 32 + lk * 8);
    }
    if (tid < 128) {
        int gg = tid >> 5, uu = tid & 31;
        int grow = gg * 512 + u0 + uu;
        bias_s[tid] = d ? (bib[grow] + bhb[grow]) : (bif[grow] + bhf[grow]);
    }
    if (tid < 224) {
        int tg = tid >> 5, uu = tid & 31;
        wout_s[tg * 33 + uu] = wout[(size_t)tg * 1024 + d * 512 + u0 + uu];
    }
    // c-state: thread -> (b = tid>>4, units uh*2, uh*2+1)
    const int cb = tid >> 4, uh = tid & 15;
    float cst[2];
    {
        const float* cr = c0 + ((size_t)(d * 64) + B0 + cb) * 512 + u0 + uh * 2;
        cst[0] = cr[0]; cst[1] = cr[1];
    }
    __syncthreads();

    const int gb = B0 + ln;                 // this lane's global batch
    f32x4 xacc0, xacc1;

    // x-phase: accumulates x_t . W_ih^T (B-frags streamed from L2)
    auto x_phase = [&](int tnext) {
        f32x4 a0a = {0,0,0,0}, a0b = {0,0,0,0}, a1a = {0,0,0,0}, a1b = {0,0,0,0};
        const size_t row0 = (size_t)(w * 512 + u0 + ln);
        const size_t row1 = row0 + 16;
#pragma unroll
        for (int kb = 0; kb < 16; ++kb) {
            bf16x8 A;
            if (xb) {
                A = *(const bf16x8*)(xb + ((size_t)gb * 512 + tnext) * 512 + kb * 32 + lk * 8);
            } else {
                int tok = sent[gb * 512 + tnext];
                const float* xr = emb + (size_t)tok * 512 + kb * 32 + lk * 8;
                float4 f0 = *(const float4*)(xr);
                float4 f1 = *(const float4*)(xr + 4);
                abf t;
                const float* pv = (const float*)&f0;
#pragma unroll
                for (int j = 0; j < 4; ++j) t.e[j] = (ushort)rtn_bf16(pv[j]);
                pv = (const float*)&f1;
#pragma unroll
                for (int j = 0; j < 4; ++j) t.e[4 + j] = (ushort)rtn_bf16(pv[j]);
                A = t.v;
            }
            bf16x8 Bx0 = *(const bf16x8*)(wip + row0 * 512 + kb * 32 + lk * 8);
            bf16x8 Bx1 = *(const bf16x8*)(wip + row1 * 512 + kb * 32 + lk * 8);
            if (kb & 1) { a0b = MFMA(A, Bx0, a0b); a1b = MFMA(A, Bx1, a1b); }
            else        { a0a = MFMA(A, Bx0, a0a); a1a = MFMA(A, Bx1, a1a); }
        }
        xacc0 = a0a + a0b;
        xacc1 = a1a + a1b;
    };

    x_phase(d ? 511 : 0);

    const char* hsb = (const char*)hstage;
    const int hx = (ln & 7) << 4;           // read-side row swizzle

#define AL(P) __hip_atomic_load((P), __ATOMIC_RELAXED, __HIP_MEMORY_SCOPE_AGENT)

    for (int s = 0; s < 512; ++s) {
        const int t = d ? (511 - s) : s;

        // ---- wait for all 16 producer blocks: ONE packed 64B flag line ----
        if (s > 0 && w == 0) {
            const int* fp = flags + (g << 4) + (L & 15);
            while (true) {
                int v = AL(fp);
                if (__all(v >= s)) break;
                __builtin_amdgcn_s_sleep(1);
            }
        }
        __syncthreads();

        // ---- co-op stage: lane-contiguous 16B/thread x 4 passes ----
        if (s > 0) {
            const u64* hq = (const u64*)(hglob + ((size_t)((s & 1) * 2 + d) * 64 + B0) * 512);
            u64 sv0 = AL(hq + tid * 2);          u64 sv1 = AL(hq + tid * 2 + 1);
            u64 sv2 = AL(hq + 512 + tid * 2);    u64 sv3 = AL(hq + 512 + tid * 2 + 1);
            u64 sv4 = AL(hq + 1024 + tid * 2);   u64 sv5 = AL(hq + 1024 + tid * 2 + 1);
            u64 sv6 = AL(hq + 1536 + tid * 2);   u64 sv7 = AL(hq + 1536 + tid * 2 + 1);
            __builtin_amdgcn_s_waitcnt(0);
            __builtin_amdgcn_sched_barrier(0);
            char* hd = (char*)hstage;
            const int c_ = (tid & 63) * 16;
            const int r_ = tid >> 6;
            {
                int rr = r_;
                char* a = hd + rr * 1024 + (c_ ^ ((rr & 7) << 4));
                *(u64*)a = sv0; *(u64*)(a + 8) = sv1;
            }
            {
                int rr = r_ + 4;
                char* a = hd + rr * 1024 + (c_ ^ ((rr & 7) << 4));
                *(u64*)a = sv2; *(u64*)(a + 8) = sv3;
            }
            {
                int rr = r_ + 8;
                char* a = hd + rr * 1024 + (c_ ^ ((rr & 7) << 4));
                *(u64*)a = sv4; *(u64*)(a + 8) = sv5;
            }
            {
                int rr = r_ + 12;
                char* a = hd + rr * 1024 + (c_ ^ ((rr & 7) << 4));
                *(u64*)a = sv6; *(u64*)(a + 8) = sv7;
            }
        }
        __syncthreads();

        // ---- h-phase MFMA onto x partials ----
        f32x4 f0a = xacc0, f0b = {0,0,0,0}, f1a = xacc1, f1b = {0,0,0,0};
        if (s == 0) {
            const float* hr = h0 + ((size_t)(d * 64) + gb) * 512;
#pragma unroll
            for (int kb = 0; kb < 16; ++kb) {
                float4 q0 = *(const float4*)(hr + kb * 32 + lk * 8);
                float4 q1 = *(const float4*)(hr + kb * 32 + lk * 8 + 4);
                abf A;
                const float* pv = (const float*)&q0;
#pragma unroll
                for (int j = 0; j < 4; ++j) A.e[j] = (ushort)rtn_bf16(pv[j]);
                pv = (const float*)&q1;
#pragma unroll
                for (int j = 0; j < 4; ++j) A.e[4 + j] = (ushort)rtn_bf16(pv[j]);
                if (kb & 1) { f0b = MFMA(A.v, Bh[0][kb], f0b); f1b = MFMA(A.v, Bh[1][kb], f1b); }
                else        { f0a = MFMA(A.v, Bh[0][kb], f0a); f1a = MFMA(A.v, Bh[1][kb], f1a); }
            }
        } else {
            abf A[16];
#pragma unroll
            for (int kb = 0; kb < 16; ++kb)
                A[kb].v = *(const bf16x8*)(hsb + ln * 1024 + ((kb * 64 + lk * 16) ^ hx));
#pragma unroll
            for (int kb = 0; kb < 16; ++kb) {
                if (kb & 1) { f0b = MFMA(A[kb].v, Bh[0][kb], f0b); f1b = MFMA(A[kb].v, Bh[1][kb], f1b); }
                else        { f0a = MFMA(A[kb].v, Bh[0][kb], f0a); f1a = MFMA(A[kb].v, Bh[1][kb], f1a); }
            }
        }
        f32x4 g0 = f0a + f0b, g1 = f1a + f1b;

        // ---- gate sums -> LDS: C row = batch lk*4+r, col = unit ----
#pragma unroll
        for (int r = 0; r < 4; ++r) {
            int b = lk * 4 + r;
            sums_s[w * 528 + b * 33 + ln]      = g0[r];
            sums_s[w * 528 + b * 33 + 16 + ln] = g1[r];
        }
        __syncthreads();

        // ---- cell update: all 256 threads, 2 (b,u) pairs; h-store fires ----
        {
            u32 pk = 0;
#pragma unroll
            for (int e = 0; e < 2; ++e) {
                int u = uh * 2 + e;
                float si = sums_s[0 * 528 + cb * 33 + u] + bias_s[u];
                float sf = sums_s[1 * 528 + cb * 33 + u] + bias_s[32 + u];
                float sg = sums_s[2 * 528 + cb * 33 + u] + bias_s[64 + u];
                float so = sums_s[3 * 528 + cb * 33 + u] + bias_s[96 + u];
                float ig = 1.f / (1.f + expf(-si));
                float fg = 1.f / (1.f + expf(-sf));
                float gv = tanhf(sg);
                float og = 1.f / (1.f + expf(-so));
                float cn = fg * cst[e] + ig * gv;
                cst[e] = cn;
                float hh = og * tanhf(cn);
                hv_s[cb * 33 + u] = hh;
                pk |= rtn_bf16(hh) << (16 * e);
            }
            u32* dst = (u32*)(hglob + ((size_t)(((s + 1) & 1) * 2 + d) * 64 + B0 + cb) * 512 + u0 + uh * 2);
            __hip_atomic_store(dst, pk, __ATOMIC_RELAXED, __HIP_MEMORY_SCOPE_AGENT);
        }
        __syncthreads();          // hv_s visible to logits readers

        // ---- tag-logit partials every step (acks hidden under x_phase) ----
        if (tid >= 144) {
            int q = tid - 144, tg = q >> 4, b = q & 15;
            float a = 0.f;
#pragma unroll
            for (int u = 0; u < 32; ++u)
                a = fmaf(hv_s[b * 33 + u], wout_s[tg * 33 + u], a);
            if (partial)
                __builtin_nontemporal_store(a, partial +
                    ((size_t)t * 64 + B0 + b) * 224 + (slot * 2 + d) * 7 + tg);
            else
                atomicAdd(&logits[((size_t)t * 64 + B0 + b) * NTAG + tg], a);
        }

        // ---- next-step x partials: h-store/logits acks drain under this ----
        if (s < 511) x_phase(d ? (510 - s) : (s + 1));

        // ---- drain everything, then arrive (parallel flag store) ----
        __builtin_amdgcn_s_waitcnt(0);
        __syncthreads();
        if (s < 511 && tid == 0)
            __hip_atomic_store(flags + (g << 4) + slot, s + 1,
                               __ATOMIC_RELAXED, __HIP_MEMORY_SCOPE_AGENT);
    }
#undef AL
}

// ---------------------------------------------------------------------------
// Viterbi decode: one wave per batch (lanes 0..6 = tags), byte backpointers.
// If `partial` is set, first reduce the 32 per-(slot,dir) partials.
// ---------------------------------------------------------------------------
__global__ __launch_bounds__(256) void viterbi_kernel(
    const float* __restrict__ logits, const float* __restrict__ partial,
    const float* __restrict__ bout, const float* __restrict__ trans,
    unsigned char* __restrict__ bp,   // [64][512][8]
    float* __restrict__ out)          // [64 scores][64*512 paths]
{
    __shared__ float Ls[4][512][7];
    const int tid = threadIdx.x;
    const int b0 = blockIdx.x << 2;

    if (partial) {
        for (int idx2 = tid; idx2 < 2048; idx2 += 256) {
            int bl = idx2 >> 9, t = idx2 & 511;
            const float* pp = partial + ((size_t)t * 64 + b0 + bl) * 224;
            float a0=0,a1=0,a2=0,a3=0,a4=0,a5=0,a6=0;
#pragma unroll 8
            for (int c = 0; c < 32; ++c) {
                const float* q = pp + c * 7;
                a0 += q[0]; a1 += q[1]; a2 += q[2]; a3 += q[3];
                a4 += q[4]; a5 += q[5]; a6 += q[6];
            }
            Ls[bl][t][0] = a0 + bout[0]; Ls[bl][t][1] = a1 + bout[1];
            Ls[bl][t][2] = a2 + bout[2]; Ls[bl][t][3] = a3 + bout[3];
            Ls[bl][t][4] = a4 + bout[4]; Ls[bl][t][5] = a5 + bout[5];
            Ls[bl][t][6] = a6 + bout[6];
        }
    } else {
        for (int idx = tid; idx < 4 * 512 * 7; idx += 256) {
            int bl = idx / 3584;
            int rem = idx - bl * 3584;
            int t = rem / 7;
            int tg = rem - t * 7;
            Ls[bl][t][tg] = logits[((size_t)t * 64 + b0 + bl) * 7 + tg] + bout[tg];
        }
    }
    __syncthreads();

    const int w = tid >> 6;
    const int lane = tid & 63;
    const int b = b0 + w;
    const int k = lane;

    float tr[7];
#pragma unroll
    for (int j = 0; j < 7; ++j) tr[j] = (k < 7) ? trans[j * 7 + k] : -1e30f;
    float prev = (k < 7) ? Ls[w][0][k] : -1e30f;
    unsigned char* bpb = bp + (size_t)b * 512 * 8;

    for (int t = 1; t < 512; ++t) {
        float best = __shfl(prev, 0, 64) + tr[0];
        int bj = 0;
#pragma unroll
        for (int j = 1; j < 7; ++j) {
            float v = __shfl(prev, j, 64) + tr[j];
            if (v > best) { best = v; bj = j; }   // strict > = first argmax
        }
        float lv = (k < 7) ? Ls[w][t][k] : 0.f;
        if (k < 7) bpb[t * 8 + k] = (unsigned char)bj;
        prev = lv + best;
    }

    float pv[7];
#pragma unroll
    for (int j = 0; j < 7; ++j) pv[j] = __shfl(prev, j, 64);
    float best = pv[0]; int bj = 0;
#pragma unroll
    for (int j = 1; j < 7; ++j) if (pv[j] > best) { best = pv[j]; bj = j; }
    if (lane == 0) {
        out[b] = best;
        out[64 + (size_t)b * 512 + 511] = (float)bj;
    }

    int cur = bj;
    for (int tc = 448; tc >= 0; tc -= 64) {
        int t = tc + lane;
        u64 row = *(const u64*)(bpb + (size_t)t * 8);
        for (int i = 63; i >= 0; --i) {
            int t2 = tc + i;
            if (t2 < 1) break;
            u64 r = __shfl(row, i, 64);
            cur = (int)((r >> (cur * 8)) & 0xFF);
            if (lane == 0) out[64 + (size_t)b * 512 + (t2 - 1)] = (float)cur;
        }
    }
}

// ---------------------------------------------------------------------------
extern "C" void kernel_launch(void* const* d_in, const int* in_sizes, int n_in,
                              void* d_out, int out_size, void* d_ws, size_t ws_size,
                              hipStream_t stream)
{
    (void)in_sizes; (void)n_in; (void)out_size;
    const int*   sent = (const int*)d_in[0];
    const float* emb  = (const float*)d_in[1];
    const float* wif  = (const float*)d_in[2];
    const float* whf  = (const float*)d_in[3];
    const float* bif  = (const float*)d_in[4];
    const float* bhf  = (const float*)d_in[5];
    const float* wib  = (const float*)d_in[6];
    const float* whb  = (const float*)d_in[7];
    const float* bib  = (const float*)d_in[8];
    const float* bhb  = (const float*)d_in[9];
    const float* wout = (const float*)d_in[10];
    const float* bout = (const float*)d_in[11];
    const float* h0   = (const float*)d_in[12];
    const float* c0   = (const float*)d_in[13];
    const float* trans= (const float*)d_in[14];
    float* out = (float*)d_out;

    // ws: logits(917504) | flags(8192; 128 used) | hglob(262144) | bp(262144)
    //     | planes(8MB) | xb(32MB opt) | partial(29.36MB opt)
    char* p = (char*)d_ws;
    float*  logits = (float*)p;            p += 917504;
    int*    flags  = (int*)p;              p += 8192;
    ushort* hglob  = (ushort*)p;           p += 2 * 2 * 64 * 512 * 2;   // 262144
    unsigned char* bp = (unsigned char*)p; p += 262144;
    ushort* planes = (ushort*)p;           p += 4 * 1048576 * 2;        // 8 MB
    size_t base_need = (size_t)(p - (char*)d_ws);
    ushort* xb = nullptr;
    float*  partial = nullptr;
    if (ws_size >= base_need + (size_t)64 * 512 * 512 * 2) {
        xb = (ushort*)p;  p += (size_t)64 * 512 * 512 * 2;              // 32 MB
        if (ws_size >= (size_t)(p - (char*)d_ws) + (size_t)512 * 64 * 224 * 4)
            partial = (float*)p;                                        // 29.36 MB
    }

    hipMemsetAsync(d_ws, 0, 917504 + 8192, stream);   // logits + flags
    prep_w_kernel<<<2048, 256, 0, stream>>>(wif, whf, wib, whb, planes);
    if (xb) prep_x_kernel<<<8192, 256, 0, stream>>>(sent, emb, xb);
    lstm_mfma_kernel<<<128, 256, 0, stream>>>(
        sent, emb, planes, xb, bif, bhf, bib, bhb,
        wout, h0, c0, hglob, logits, partial, flags);
    viterbi_kernel<<<16, 256, 0, stream>>>(logits, partial, bout, trans, bp, out);
}

// Round 7
// 5096.725 us; speedup vs baseline: 2.1271x; 1.0430x over previous
//
#include <hip/hip_runtime.h>
#include <cstdint>
#include <cstddef>

#define NTAG 7

typedef unsigned int u32;
typedef unsigned long long u64;
using bf16x8 = __attribute__((ext_vector_type(8))) short;
using f32x4  = __attribute__((ext_vector_type(4))) float;
using i32x4  = __attribute__((ext_vector_type(4))) int;

#define MFMA(A,B,C) __builtin_amdgcn_mfma_f32_16x16x32_bf16((A),(B),(C),0,0,0)

union abf { u64 q[2]; ushort e[8]; bf16x8 v; };
union qv  { i32x4 v; u64 q[2]; };

__device__ __forceinline__ u32 rtn_bf16(float f) {   // round-to-nearest-even
    u32 b = __float_as_uint(f);
    return (b + 0x7fffu + ((b >> 16) & 1u)) >> 16;
}

// ---------------------------------------------------------------------------
// Prep 1: fp32 -> bf16 (RTN) weight planes. order: 0=wif 1=whf 2=wib 3=whb
// ---------------------------------------------------------------------------
__global__ __launch_bounds__(256) void prep_w_kernel(
    const float* __restrict__ wif, const float* __restrict__ whf,
    const float* __restrict__ wib, const float* __restrict__ whb,
    ushort* __restrict__ planes)
{
    int f = blockIdx.x * 256 + threadIdx.x;          // x8 elems
    int mat = f >> 17;
    int i8 = (f & 0x1FFFF) << 3;
    const float* src = (mat == 0) ? wif : (mat == 1) ? whf : (mat == 2) ? wib : whb;
    float4 v0 = *(const float4*)(src + i8);
    float4 v1 = *(const float4*)(src + i8 + 4);
    ushort o[8];
    const float* pv = (const float*)&v0;
#pragma unroll
    for (int j = 0; j < 4; ++j) o[j] = (ushort)rtn_bf16(pv[j]);
    pv = (const float*)&v1;
#pragma unroll
    for (int j = 0; j < 4; ++j) o[4 + j] = (ushort)rtn_bf16(pv[j]);
    ushort* dst = planes + ((size_t)mat << 20) + i8;
    *(ushort4*)dst = make_ushort4(o[0], o[1], o[2], o[3]);
    *(ushort4*)(dst + 4) = make_ushort4(o[4], o[5], o[6], o[7]);
}

// ---------------------------------------------------------------------------
// Prep 2: xb[b][t][e] = bf16(emb[sent[b][t]][e])
// ---------------------------------------------------------------------------
__global__ __launch_bounds__(256) void prep_x_kernel(
    const int* __restrict__ sent, const float* __restrict__ emb,
    ushort* __restrict__ xb)
{
    long f = (long)blockIdx.x * 256 + threadIdx.x;   // x8 elems
    long e8 = f << 3;
    int bt = (int)(e8 >> 9);
    int e  = (int)(e8 & 511);
    int tok = sent[bt];
    const float* src = emb + (size_t)tok * 512 + e;
    float4 v0 = *(const float4*)(src);
    float4 v1 = *(const float4*)(src + 4);
    ushort o[8];
    const float* pv = (const float*)&v0;
#pragma unroll
    for (int j = 0; j < 4; ++j) o[j] = (ushort)rtn_bf16(pv[j]);
    pv = (const float*)&v1;
#pragma unroll
    for (int j = 0; j < 4; ++j) o[4 + j] = (ushort)rtn_bf16(pv[j]);
    ushort* dst = xb + e8;
    *(ushort4*)dst = make_ushort4(o[0], o[1], o[2], o[3]);
    *(ushort4*)(dst + 4) = make_ushort4(o[4], o[5], o[6], o[7]);
}

// ---------------------------------------------------------------------------
// Main persistent kernel: 128 blocks x 256 thr (4 waves), 1 block/CU.
// group g = blockIdx&7 = (dir d, batch-quarter bq: 16 batches); slot =
// blockIdx>>3 -> 32 units. wave w = gate w, 2 n-tiles of 16 units.
// NEW this round: runtime XCD-co-location handshake. If all 16 blocks of a
// group report the same HW_REG_XCC_ID (and it differs from the neighbor
// group's -> getreg sanity), the group's h/flag exchange runs with sc0-only
// ops: L1-bypassed, XCD-L2-coherent, PRIVATE per group (zero cross-group
// MALL contention, ~200cy RTT). Otherwise: byte-identical R6 agent path.
// Also: logits partial stores moved after the flag post (acks off the
// pre-flag waitcnt).
// ---------------------------------------------------------------------------
__global__ __launch_bounds__(256, 1) void lstm_mfma_kernel(
    const int* __restrict__ sent, const float* __restrict__ emb,
    const ushort* __restrict__ planes, const ushort* __restrict__ xb,
    const float* __restrict__ bif, const float* __restrict__ bhf,
    const float* __restrict__ bib, const float* __restrict__ bhb,
    const float* __restrict__ wout,
    const float* __restrict__ h0, const float* __restrict__ c0,
    ushort* __restrict__ hglob,   // [2 par][2 d][64 b][512] bf16
    float* __restrict__ logits,   // [512][64][7] atomic fallback
    float* __restrict__ partial,  // [512][64][32][7] private partials (opt)
    int* __restrict__ flags)      // [0..127]: flag lines; [512..639]: xcc tab
{
    __shared__ __align__(16) ushort hstage[16 * 512];   // 16384 B, XOR-swz rows
    __shared__ float sums_s[4 * 16 * 33];               //  8448 B
    __shared__ float hv_s[16 * 33];                     //  2112 B
    __shared__ float bias_s[4 * 32];                    //   512 B
    __shared__ float wout_s[7 * 33];                    //   924 B
    __shared__ int   fast_s;

    const int tid = threadIdx.x;
    const int w   = tid >> 6;       // wave = gate
    const int L   = tid & 63;
    const int ln  = L & 15;
    const int lk  = L >> 4;
    const int g   = blockIdx.x & 7;
    const int slot= blockIdx.x >> 3;
    const int d   = g & 1;
    const int bq  = g >> 1;
    const int B0  = bq << 4;
    const int u0  = slot << 5;

    const ushort* wip = planes + ((size_t)(d ? 2 : 0) << 20);
    const ushort* whp = planes + ((size_t)(d ? 3 : 1) << 20);

    // register-resident W_hh B-frags: rows = gate w, units u0 + h*16 + ln
    bf16x8 Bh[2][16];
#pragma unroll
    for (int h = 0; h < 2; ++h) {
        const size_t row = (size_t)(w * 512 + u0 + h * 16 + ln);
#pragma unroll
        for (int kb = 0; kb < 16; ++kb)
            Bh[h][kb] = *(const bf16x8*)(whp + row * 512 + kb * 32 + lk * 8);
    }
    if (tid < 128) {
        int gg = tid >> 5, uu = tid & 31;
        int grow = gg * 512 + u0 + uu;
        bias_s[tid] = d ? (bib[grow] + bhb[grow]) : (bif[grow] + bhf[grow]);
    }
    if (tid < 224) {
        int tg = tid >> 5, uu = tid & 31;
        wout_s[tg * 33 + uu] = wout[(size_t)tg * 1024 + d * 512 + u0 + uu];
    }
    // c-state: thread -> (b = tid>>4, units uh*2, uh*2+1)
    const int cb = tid >> 4, uh = tid & 15;
    float cst[2];
    {
        const float* cr = c0 + ((size_t)(d * 64) + B0 + cb) * 512 + u0 + uh * 2;
        cst[0] = cr[0]; cst[1] = cr[1];
    }

    // ---- XCD co-location handshake (one-time) ----
    {
        // HW_REG_XCC_ID: id=20, offset=0, size=4 -> imm = 20 | (3<<11)
        int xcc = (int)__builtin_amdgcn_s_getreg(20 | (3 << 11));
        int* tab = flags + 512;
        if (tid == 0)
            __hip_atomic_store(tab + (g << 4) + slot, (xcc & 0xF) + 1,
                               __ATOMIC_RELAXED, __HIP_MEMORY_SCOPE_AGENT);
        if (w == 0) {
            const int* myp = tab + (g << 4) + (L & 15);
            const int* nbp = tab + ((g ^ 1) << 4);
            const int* pp = (L == 16) ? nbp : myp;
            int v;
            while (true) {
                v = __hip_atomic_load(pp, __ATOMIC_RELAXED, __HIP_MEMORY_SCOPE_AGENT);
                if (__all(v > 0)) break;
                __builtin_amdgcn_s_sleep(2);
            }
            int v0 = __shfl(v, 0, 64);
            int vn = __shfl(v, 16, 64);
            int uni = __all((L < 16) ? (v == v0) : 1);
            if (L == 0) fast_s = (uni && (v0 != vn)) ? 1 : 0;
        }
    }
    __syncthreads();
    const int fast = fast_s;

    const int gb = B0 + ln;                 // this lane's global batch
    f32x4 xacc0, xacc1;

    // x-phase: accumulates x_t . W_ih^T (B-frags streamed from L2)
    auto x_phase = [&](int tnext) {
        f32x4 a0a = {0,0,0,0}, a0b = {0,0,0,0}, a1a = {0,0,0,0}, a1b = {0,0,0,0};
        const size_t row0 = (size_t)(w * 512 + u0 + ln);
        const size_t row1 = row0 + 16;
#pragma unroll
        for (int kb = 0; kb < 16; ++kb) {
            bf16x8 A;
            if (xb) {
                A = *(const bf16x8*)(xb + ((size_t)gb * 512 + tnext) * 512 + kb * 32 + lk * 8);
            } else {
                int tok = sent[gb * 512 + tnext];
                const float* xr = emb + (size_t)tok * 512 + kb * 32 + lk * 8;
                float4 f0 = *(const float4*)(xr);
                float4 f1 = *(const float4*)(xr + 4);
                abf t;
                const float* pv = (const float*)&f0;
#pragma unroll
                for (int j = 0; j < 4; ++j) t.e[j] = (ushort)rtn_bf16(pv[j]);
                pv = (const float*)&f1;
#pragma unroll
                for (int j = 0; j < 4; ++j) t.e[4 + j] = (ushort)rtn_bf16(pv[j]);
                A = t.v;
            }
            bf16x8 Bx0 = *(const bf16x8*)(wip + row0 * 512 + kb * 32 + lk * 8);
            bf16x8 Bx1 = *(const bf16x8*)(wip + row1 * 512 + kb * 32 + lk * 8);
            if (kb & 1) { a0b = MFMA(A, Bx0, a0b); a1b = MFMA(A, Bx1, a1b); }
            else        { a0a = MFMA(A, Bx0, a0a); a1a = MFMA(A, Bx1, a1a); }
        }
        xacc0 = a0a + a0b;
        xacc1 = a1a + a1b;
    };

    x_phase(d ? 511 : 0);

    const char* hsb = (const char*)hstage;
    const int hx = (ln & 7) << 4;           // read-side row swizzle

#define AL(P) __hip_atomic_load((P), __ATOMIC_RELAXED, __HIP_MEMORY_SCOPE_AGENT)

    for (int s = 0; s < 512; ++s) {
        const int t = d ? (511 - s) : s;

        // ---- wait for all 16 producer blocks: ONE packed 64B flag line ----
        if (s > 0 && w == 0) {
            const int* fp = flags + (g << 4) + (L & 15);
            if (fast) {
                while (true) {
                    int v;
                    asm volatile("global_load_dword %0, %1, off sc0\n\t"
                                 "s_waitcnt vmcnt(0)"
                                 : "=&v"(v) : "v"(fp) : "memory");
                    if (__all(v >= s)) break;
                    __builtin_amdgcn_s_sleep(1);
                }
            } else {
                while (true) {
                    int v = AL(fp);
                    if (__all(v >= s)) break;
                    __builtin_amdgcn_s_sleep(1);
                }
            }
        }
        __syncthreads();

        // ---- co-op stage: lane-contiguous 16B/thread x 4 passes ----
        if (s > 0) {
            const u64* hq = (const u64*)(hglob + ((size_t)((s & 1) * 2 + d) * 64 + B0) * 512);
            qv q0, q1, q2, q3;
            if (fast) {
                const char* p0 = (const char*)hq + tid * 16;
                const char* p1 = p0 + 4096;
                const char* p2 = p0 + 8192;
                const char* p3 = p0 + 12288;
                asm volatile(
                    "global_load_dwordx4 %0, %4, off sc0\n\t"
                    "global_load_dwordx4 %1, %5, off sc0\n\t"
                    "global_load_dwordx4 %2, %6, off sc0\n\t"
                    "global_load_dwordx4 %3, %7, off sc0\n\t"
                    "s_waitcnt vmcnt(0)"
                    : "=&v"(q0.v), "=&v"(q1.v), "=&v"(q2.v), "=&v"(q3.v)
                    : "v"(p0), "v"(p1), "v"(p2), "v"(p3)
                    : "memory");
            } else {
                q0.q[0] = AL(hq + tid * 2);          q0.q[1] = AL(hq + tid * 2 + 1);
                q1.q[0] = AL(hq + 512 + tid * 2);    q1.q[1] = AL(hq + 512 + tid * 2 + 1);
                q2.q[0] = AL(hq + 1024 + tid * 2);   q2.q[1] = AL(hq + 1024 + tid * 2 + 1);
                q3.q[0] = AL(hq + 1536 + tid * 2);   q3.q[1] = AL(hq + 1536 + tid * 2 + 1);
                __builtin_amdgcn_s_waitcnt(0);
            }
            __builtin_amdgcn_sched_barrier(0);
            char* hd = (char*)hstage;
            const int c_ = (tid & 63) * 16;
            const int r_ = tid >> 6;
            {
                int rr = r_;
                char* a = hd + rr * 1024 + (c_ ^ ((rr & 7) << 4));
                *(u64*)a = q0.q[0]; *(u64*)(a + 8) = q0.q[1];
            }
            {
                int rr = r_ + 4;
                char* a = hd + rr * 1024 + (c_ ^ ((rr & 7) << 4));
                *(u64*)a = q1.q[0]; *(u64*)(a + 8) = q1.q[1];
            }
            {
                int rr = r_ + 8;
                char* a = hd + rr * 1024 + (c_ ^ ((rr & 7) << 4));
                *(u64*)a = q2.q[0]; *(u64*)(a + 8) = q2.q[1];
            }
            {
                int rr = r_ + 12;
                char* a = hd + rr * 1024 + (c_ ^ ((rr & 7) << 4));
                *(u64*)a = q3.q[0]; *(u64*)(a + 8) = q3.q[1];
            }
        }
        __syncthreads();

        // ---- h-phase MFMA onto x partials ----
        f32x4 f0a = xacc0, f0b = {0,0,0,0}, f1a = xacc1, f1b = {0,0,0,0};
        if (s == 0) {
            const float* hr = h0 + ((size_t)(d * 64) + gb) * 512;
#pragma unroll
            for (int kb = 0; kb < 16; ++kb) {
                float4 q0f = *(const float4*)(hr + kb * 32 + lk * 8);
                float4 q1f = *(const float4*)(hr + kb * 32 + lk * 8 + 4);
                abf A;
                const float* pv = (const float*)&q0f;
#pragma unroll
                for (int j = 0; j < 4; ++j) A.e[j] = (ushort)rtn_bf16(pv[j]);
                pv = (const float*)&q1f;
#pragma unroll
                for (int j = 0; j < 4; ++j) A.e[4 + j] = (ushort)rtn_bf16(pv[j]);
                if (kb & 1) { f0b = MFMA(A.v, Bh[0][kb], f0b); f1b = MFMA(A.v, Bh[1][kb], f1b); }
                else        { f0a = MFMA(A.v, Bh[0][kb], f0a); f1a = MFMA(A.v, Bh[1][kb], f1a); }
            }
        } else {
            abf A[16];
#pragma unroll
            for (int kb = 0; kb < 16; ++kb)
                A[kb].v = *(const bf16x8*)(hsb + ln * 1024 + ((kb * 64 + lk * 16) ^ hx));
#pragma unroll
            for (int kb = 0; kb < 16; ++kb) {
                if (kb & 1) { f0b = MFMA(A[kb].v, Bh[0][kb], f0b); f1b = MFMA(A[kb].v, Bh[1][kb], f1b); }
                else        { f0a = MFMA(A[kb].v, Bh[0][kb], f0a); f1a = MFMA(A[kb].v, Bh[1][kb], f1a); }
            }
        }
        f32x4 g0 = f0a + f0b, g1 = f1a + f1b;

        // ---- gate sums -> LDS: C row = batch lk*4+r, col = unit ----
#pragma unroll
        for (int r = 0; r < 4; ++r) {
            int b = lk * 4 + r;
            sums_s[w * 528 + b * 33 + ln]      = g0[r];
            sums_s[w * 528 + b * 33 + 16 + ln] = g1[r];
        }
        __syncthreads();

        // ---- cell update: all 256 threads, 2 (b,u) pairs; h-store fires ----
        {
            u32 pk = 0;
#pragma unroll
            for (int e = 0; e < 2; ++e) {
                int u = uh * 2 + e;
                float si = sums_s[0 * 528 + cb * 33 + u] + bias_s[u];
                float sf = sums_s[1 * 528 + cb * 33 + u] + bias_s[32 + u];
                float sg = sums_s[2 * 528 + cb * 33 + u] + bias_s[64 + u];
                float so = sums_s[3 * 528 + cb * 33 + u] + bias_s[96 + u];
                float ig = 1.f / (1.f + expf(-si));
                float fg = 1.f / (1.f + expf(-sf));
                float gv = tanhf(sg);
                float og = 1.f / (1.f + expf(-so));
                float cn = fg * cst[e] + ig * gv;
                cst[e] = cn;
                float hh = og * tanhf(cn);
                hv_s[cb * 33 + u] = hh;
                pk |= rtn_bf16(hh) << (16 * e);
            }
            u32* dst = (u32*)(hglob + ((size_t)(((s + 1) & 1) * 2 + d) * 64 + B0 + cb) * 512 + u0 + uh * 2);
            if (fast)
                asm volatile("global_store_dword %0, %1, off sc0"
                             :: "v"(dst), "v"(pk) : "memory");
            else
                __hip_atomic_store(dst, pk, __ATOMIC_RELAXED, __HIP_MEMORY_SCOPE_AGENT);
        }
        __syncthreads();          // hv_s visible to logits readers

        // ---- next-step x partials: h-store acks drain under this ----
        if (s < 511) x_phase(d ? (510 - s) : (s + 1));

        // ---- drain, then arrive (parallel flag store) ----
        __builtin_amdgcn_s_waitcnt(0);
        __syncthreads();
        if (s < 511 && tid == 0) {
            int* fsp = flags + (g << 4) + slot;
            int val = s + 1;
            if (fast)
                asm volatile("global_store_dword %0, %1, off sc0"
                             :: "v"(fsp), "v"(val) : "memory");
            else
                __hip_atomic_store(fsp, val, __ATOMIC_RELAXED, __HIP_MEMORY_SCOPE_AGENT);
        }

        // ---- tag-logit partials AFTER flag (acks overlap next poll) ----
        if (tid >= 144) {
            int q = tid - 144, tg = q >> 4, b = q & 15;
            float a = 0.f;
#pragma unroll
            for (int u = 0; u < 32; ++u)
                a = fmaf(hv_s[b * 33 + u], wout_s[tg * 33 + u], a);
            if (partial)
                __builtin_nontemporal_store(a, partial +
                    ((size_t)t * 64 + B0 + b) * 224 + (slot * 2 + d) * 7 + tg);
            else
                atomicAdd(&logits[((size_t)t * 64 + B0 + b) * NTAG + tg], a);
        }
    }
#undef AL
}

// ---------------------------------------------------------------------------
// Viterbi decode: one wave per batch (lanes 0..6 = tags), byte backpointers.
// If `partial` is set, first reduce the 32 per-(slot,dir) partials.
// ---------------------------------------------------------------------------
__global__ __launch_bounds__(256) void viterbi_kernel(
    const float* __restrict__ logits, const float* __restrict__ partial,
    const float* __restrict__ bout, const float* __restrict__ trans,
    unsigned char* __restrict__ bp,   // [64][512][8]
    float* __restrict__ out)          // [64 scores][64*512 paths]
{
    __shared__ float Ls[4][512][7];
    const int tid = threadIdx.x;
    const int b0 = blockIdx.x << 2;

    if (partial) {
        for (int idx2 = tid; idx2 < 2048; idx2 += 256) {
            int bl = idx2 >> 9, t = idx2 & 511;
            const float* pp = partial + ((size_t)t * 64 + b0 + bl) * 224;
            float a0=0,a1=0,a2=0,a3=0,a4=0,a5=0,a6=0;
#pragma unroll 8
            for (int c = 0; c < 32; ++c) {
                const float* q = pp + c * 7;
                a0 += q[0]; a1 += q[1]; a2 += q[2]; a3 += q[3];
                a4 += q[4]; a5 += q[5]; a6 += q[6];
            }
            Ls[bl][t][0] = a0 + bout[0]; Ls[bl][t][1] = a1 + bout[1];
            Ls[bl][t][2] = a2 + bout[2]; Ls[bl][t][3] = a3 + bout[3];
            Ls[bl][t][4] = a4 + bout[4]; Ls[bl][t][5] = a5 + bout[5];
            Ls[bl][t][6] = a6 + bout[6];
        }
    } else {
        for (int idx = tid; idx < 4 * 512 * 7; idx += 256) {
            int bl = idx / 3584;
            int rem = idx - bl * 3584;
            int t = rem / 7;
            int tg = rem - t * 7;
            Ls[bl][t][tg] = logits[((size_t)t * 64 + b0 + bl) * 7 + tg] + bout[tg];
        }
    }
    __syncthreads();

    const int w = tid >> 6;
    const int lane = tid & 63;
    const int b = b0 + w;
    const int k = lane;

    float tr[7];
#pragma unroll
    for (int j = 0; j < 7; ++j) tr[j] = (k < 7) ? trans[j * 7 + k] : -1e30f;
    float prev = (k < 7) ? Ls[w][0][k] : -1e30f;
    unsigned char* bpb = bp + (size_t)b * 512 * 8;

    for (int t = 1; t < 512; ++t) {
        float best = __shfl(prev, 0, 64) + tr[0];
        int bj = 0;
#pragma unroll
        for (int j = 1; j < 7; ++j) {
            float v = __shfl(prev, j, 64) + tr[j];
            if (v > best) { best = v; bj = j; }   // strict > = first argmax
        }
        float lv = (k < 7) ? Ls[w][t][k] : 0.f;
        if (k < 7) bpb[t * 8 + k] = (unsigned char)bj;
        prev = lv + best;
    }

    float pv[7];
#pragma unroll
    for (int j = 0; j < 7; ++j) pv[j] = __shfl(prev, j, 64);
    float best = pv[0]; int bj = 0;
#pragma unroll
    for (int j = 1; j < 7; ++j) if (pv[j] > best) { best = pv[j]; bj = j; }
    if (lane == 0) {
        out[b] = best;
        out[64 + (size_t)b * 512 + 511] = (float)bj;
    }

    int cur = bj;
    for (int tc = 448; tc >= 0; tc -= 64) {
        int t = tc + lane;
        u64 row = *(const u64*)(bpb + (size_t)t * 8);
        for (int i = 63; i >= 0; --i) {
            int t2 = tc + i;
            if (t2 < 1) break;
            u64 r = __shfl(row, i, 64);
            cur = (int)((r >> (cur * 8)) & 0xFF);
            if (lane == 0) out[64 + (size_t)b * 512 + (t2 - 1)] = (float)cur;
        }
    }
}

// ---------------------------------------------------------------------------
extern "C" void kernel_launch(void* const* d_in, const int* in_sizes, int n_in,
                              void* d_out, int out_size, void* d_ws, size_t ws_size,
                              hipStream_t stream)
{
    (void)in_sizes; (void)n_in; (void)out_size;
    const int*   sent = (const int*)d_in[0];
    const float* emb  = (const float*)d_in[1];
    const float* wif  = (const float*)d_in[2];
    const float* whf  = (const float*)d_in[3];
    const float* bif  = (const float*)d_in[4];
    const float* bhf  = (const float*)d_in[5];
    const float* wib  = (const float*)d_in[6];
    const float* whb  = (const float*)d_in[7];
    const float* bib  = (const float*)d_in[8];
    const float* bhb  = (const float*)d_in[9];
    const float* wout = (const float*)d_in[10];
    const float* bout = (const float*)d_in[11];
    const float* h0   = (const float*)d_in[12];
    const float* c0   = (const float*)d_in[13];
    const float* trans= (const float*)d_in[14];
    float* out = (float*)d_out;

    // ws: logits(917504) | flags(8192; 128 flag + 128 xcc used) | hglob(262144)
    //     | bp(262144) | planes(8MB) | xb(32MB opt) | partial(29.36MB opt)
    char* p = (char*)d_ws;
    float*  logits = (float*)p;            p += 917504;
    int*    flags  = (int*)p;              p += 8192;
    ushort* hglob  = (ushort*)p;           p += 2 * 2 * 64 * 512 * 2;   // 262144
    unsigned char* bp = (unsigned char*)p; p += 262144;
    ushort* planes = (ushort*)p;           p += 4 * 1048576 * 2;        // 8 MB
    size_t base_need = (size_t)(p - (char*)d_ws);
    ushort* xb = nullptr;
    float*  partial = nullptr;
    if (ws_size >= base_need + (size_t)64 * 512 * 512 * 2) {
        xb = (ushort*)p;  p += (size_t)64 * 512 * 512 * 2;              // 32 MB
        if (ws_size >= (size_t)(p - (char*)d_ws) + (size_t)512 * 64 * 224 * 4)
            partial = (float*)p;                                        // 29.36 MB
    }

    hipMemsetAsync(d_ws, 0, 917504 + 8192, stream);   // logits + flags + xcc tab
    prep_w_kernel<<<2048, 256, 0, stream>>>(wif, whf, wib, whb, planes);
    if (xb) prep_x_kernel<<<8192, 256, 0, stream>>>(sent, emb, xb);
    lstm_mfma_kernel<<<128, 256, 0, stream>>>(
        sent, emb, planes, xb, bif, bhf, bib, bhb,
        wout, h0, c0, hglob, logits, partial, flags);
    viterbi_kernel<<<16, 256, 0, stream>>>(logits, partial, bout, trans, bp, out);
}